// Round 1
// 331.367 us; speedup vs baseline: 1.0090x; 1.0090x over previous
//
#include <hip/hip_runtime.h>

constexpr int LMAX = 8;
constexpr int NCOL = (LMAX + 1) * (LMAX + 1);   // 81
constexpr int PPB  = 32;                         // points per block
constexpr int THREADS = 64;                      // one wave
constexpr int TILE_FLOATS = PPB * NCOL;          // 2592
constexpr int TILE_VEC4   = TILE_FLOATS / 4;     // 648 = 10*64 + 8

__device__ __forceinline__ void emit_col(float* row, const float* __restrict__ F,
                                         int l, int m, float Q, float sm, float cm) {
    const int fbase = l * (l + 1) / 2;
    const int cbase = l * l + l;
    if (m == 0) {
        const float inv_sqrt2 = 0.70710678118654752440f;
        row[cbase] = F[fbase] * Q * inv_sqrt2;
    } else {
        float t = F[fbase + m] * Q;
        row[cbase - m] = t * sm;
        row[cbase + m] = t * cm;
    }
}

// Compute all columns with m = M0, M0+2, ..., <= LMAX for one point.
template <int M0>
__device__ __forceinline__ void compute_half(float* row, const float* __restrict__ F,
                                             float x, float y, float z) {
    float sm, cm, Qmm;
    if (M0 == 0) { sm = 0.0f; cm = 1.0f; Qmm = 1.0f; }
    else         { sm = y;    cm = x;    Qmm = -1.0f; }   // s1=y, c1=x, Q11=-1

#pragma unroll
    for (int m = M0; m <= LMAX; m += 2) {
        if (m > M0) {
            // advance sin/cos chain two steps: (m-2) -> (m-1) -> m
            const float s1 = x * sm + y * cm;
            const float c1 = x * cm - y * sm;
            sm = x * s1 + y * c1;
            cm = x * c1 - y * s1;
            // Q[m,m] = (2m-1)(2m-3) * Q[m-2,m-2]  (two negated factors)
            Qmm *= (float)((2 * m - 1) * (2 * m - 3));
        }
        float Qp = Qmm;                       // Q[m,m]
        emit_col(row, F, m, m, Qp, sm, cm);
        if (m < LMAX) {
            float Qc = (float)(2 * m + 1) * z * Qmm;   // Q[m+1,m]
            emit_col(row, F, m + 1, m, Qc, sm, cm);
#pragma unroll
            for (int l = m + 2; l <= LMAX; ++l) {
                const float Qn = ((float)(2 * l - 1) * z * Qc
                                  - (float)(l + m - 1) * Qp) * (1.0f / (float)(l - m));
                Qp = Qc; Qc = Qn;
                emit_col(row, F, l, m, Qc, sm, cm);
            }
        }
    }
}

__global__ __launch_bounds__(THREADS, 4) void sh_kernel(const float* __restrict__ xyz,
                                                        const float* __restrict__ F,
                                                        float* __restrict__ out, int n) {
    __shared__ float tile[TILE_FLOATS];   // 10368 B -> 15 blocks/CU
    const int lane    = threadIdx.x;
    const int p       = lane & 31;        // point within tile
    const int half    = lane >> 5;        // 0: even m, 1: odd m
    const int base_pt = blockIdx.x * PPB;
    const int i       = base_pt + p;

    float x = 0.0f, y = 0.0f, z = 1.0f;
    if (i < n) {
        x = xyz[3 * i + 0];
        y = xyz[3 * i + 1];
        z = xyz[3 * i + 2];
    }
    const float rsq  = x * x + y * y + z * z;
    const float rinv = rsqrtf(rsq);
    x *= rinv; y *= rinv; z *= rinv;

    float* row = &tile[p * NCOL];

    if (half == 0) compute_half<0>(row, F, x, y, z);
    else           compute_half<1>(row, F, x, y, z);

    __syncthreads();

    const long long tile_base = (long long)base_pt * NCOL;   // float index into out
    if (base_pt + PPB <= n) {
        // fully coalesced: contiguous 10368 B region, 16B-aligned (10368 * blockIdx)
        const float4* src = (const float4*)tile;
        float4* dst = (float4*)(out + tile_base);
#pragma unroll
        for (int k = 0; k < 10; ++k) {
            dst[k * THREADS + lane] = src[k * THREADS + lane];
        }
        // remaining 8 float4 (648 = 10*64 + 8)
        if (lane < TILE_VEC4 - 10 * THREADS) {
            dst[10 * THREADS + lane] = src[10 * THREADS + lane];
        }
    } else {
        const long long lim = (long long)n * NCOL;
        for (int k = lane; k < TILE_FLOATS; k += THREADS) {
            const long long gi = tile_base + k;
            if (gi < lim) out[gi] = tile[k];
        }
    }
}

extern "C" void kernel_launch(void* const* d_in, const int* in_sizes, int n_in,
                              void* d_out, int out_size, void* d_ws, size_t ws_size,
                              hipStream_t stream) {
    const float* xyz = (const float*)d_in[0];
    const float* F   = (const float*)d_in[1];
    float* out       = (float*)d_out;
    const int n      = in_sizes[0] / 3;
    const int grid   = (n + PPB - 1) / PPB;
    sh_kernel<<<grid, THREADS, 0, stream>>>(xyz, F, out, n);
}